// Round 16
// baseline (4494.902 us; speedup 1.0000x reference)
//
#include <hip/hip_runtime.h>
#include <cstdint>
#include <cstddef>

#define B_  2
#define S_  2048
#define D_  1024
#define HH_ 4096
#define E_  8
#define RH_ 256

typedef float  f32x4 __attribute__((ext_vector_type(4)));
typedef float  f32x2 __attribute__((ext_vector_type(2)));
typedef __bf16 bf16x8 __attribute__((ext_vector_type(8)));
typedef __bf16 bf16x4 __attribute__((ext_vector_type(4)));

// ---------------------------------------------------------------- helpers
__device__ __forceinline__ void gload_lds16(const void* g, void* l) {
  __builtin_amdgcn_global_load_lds(
      (const __attribute__((address_space(1))) unsigned int*)g,
      (__attribute__((address_space(3))) unsigned int*)l, 16, 0, 0);
}

// stage a 128x64 bf16 tile (row-major, leading dim ldK elems) into LDS linearly
__device__ __forceinline__ void stage128x64(__bf16* s, const __bf16* g, int ldK, int t) {
  const int wv = t >> 6, l = t & 63;
#pragma unroll
  for (int p = 0; p < 4; ++p) {
    const int base = p * 256 + wv * 64;      // wave-uniform flat base
    const int flat = base + l;               // per-lane
    const int row = flat >> 3, c16 = flat & 7;
    gload_lds16(g + (size_t)row * ldK + c16 * 8, s + (size_t)base * 8);
  }
}

// stage a 128x64 tile from F32 source, converting to bf16 (RNE) via registers
__device__ __forceinline__ void stage128x64_cvt(__bf16* s, const float* g, int ldK, int t) {
#pragma unroll
  for (int p = 0; p < 4; ++p) {
    const int flat = p * 256 + t;
    const int row = flat >> 3, c8 = (flat & 7) << 3;
    const float* src = g + (size_t)row * ldK + c8;
    f32x4 a = *(const f32x4*)src;
    f32x4 b = *(const f32x4*)(src + 4);
    bf16x8 o;
#pragma unroll
    for (int j2 = 0; j2 < 4; ++j2) { o[j2] = (__bf16)a[j2]; o[4 + j2] = (__bf16)b[j2]; }
    *(bf16x8*)&s[(size_t)flat * 8] = o;
  }
}

// gather-stage: row r of the tile comes from src row rowtok[r]
__device__ __forceinline__ void stage128x64_gather(__bf16* s, const __bf16* src,
                                                   int ldK, int k0,
                                                   const int* rowtok, int t) {
  const int wv = t >> 6, l = t & 63;
#pragma unroll
  for (int p = 0; p < 4; ++p) {
    const int base = p * 256 + wv * 64;
    const int flat = base + l;
    const int row = flat >> 3, c16 = flat & 7;
    const int tok = rowtok[row];
    gload_lds16(src + (size_t)tok * ldK + k0 + c16 * 8, s + (size_t)base * 8);
  }
}

__device__ __forceinline__ void mfma_tile(const __bf16* sA, const __bf16* sB,
                                          f32x4 acc[4][4], int t) {
  const int w = t >> 6, l = t & 63;
  const int wr = w >> 1, wc = w & 1;
  const int fr = l & 15, fk = (l >> 4) * 8;
#pragma unroll
  for (int kk = 0; kk < 2; ++kk) {
    bf16x8 a[4], b[4];
#pragma unroll
    for (int m = 0; m < 4; ++m)
      a[m] = *(const bf16x8*)&sA[(64 * wr + 16 * m + fr) * 64 + kk * 32 + fk];
#pragma unroll
    for (int n = 0; n < 4; ++n)
      b[n] = *(const bf16x8*)&sB[(64 * wc + 16 * n + fr) * 64 + kk * 32 + fk];
#pragma unroll
    for (int m = 0; m < 4; ++m)
#pragma unroll
      for (int n = 0; n < 4; ++n)
        acc[m][n] = __builtin_amdgcn_mfma_f32_16x16x32_bf16(a[m], b[n], acc[m][n], 0, 0, 0);
  }
}

__device__ __forceinline__ void mfma_tile2(const __bf16* sA, const __bf16* sB,
                                           const __bf16* sC, f32x4 accg[4][4],
                                           f32x4 accu[4][4], int t) {
  const int w = t >> 6, l = t & 63;
  const int wr = w >> 1, wc = w & 1;
  const int fr = l & 15, fk = (l >> 4) * 8;
#pragma unroll
  for (int kk = 0; kk < 2; ++kk) {
    bf16x8 a[4], bg[4], bu[4];
#pragma unroll
    for (int m = 0; m < 4; ++m)
      a[m] = *(const bf16x8*)&sA[(64 * wr + 16 * m + fr) * 64 + kk * 32 + fk];
#pragma unroll
    for (int n = 0; n < 4; ++n) {
      bg[n] = *(const bf16x8*)&sB[(64 * wc + 16 * n + fr) * 64 + kk * 32 + fk];
      bu[n] = *(const bf16x8*)&sC[(64 * wc + 16 * n + fr) * 64 + kk * 32 + fk];
    }
#pragma unroll
    for (int m = 0; m < 4; ++m)
#pragma unroll
      for (int n = 0; n < 4; ++n) {
        accg[m][n] = __builtin_amdgcn_mfma_f32_16x16x32_bf16(a[m], bg[n], accg[m][n], 0, 0, 0);
        accu[m][n] = __builtin_amdgcn_mfma_f32_16x16x32_bf16(a[m], bu[n], accu[m][n], 0, 0, 0);
      }
  }
}

// packed f32 FMA: d = a*b + d
__device__ __forceinline__ f32x2 pkfma(f32x2 a, f32x2 b, f32x2 d) {
  asm("v_pk_fma_f32 %0, %1, %2, %0" : "+v"(d) : "v"(a), "v"(b));
  return d;
}

// inline HW transcendentals (no libm calls in the scan)
__device__ __forceinline__ float fexp(float x) {
  return __builtin_amdgcn_exp2f(x * 1.44269504088896f);
}
__device__ __forceinline__ float fsig(float x) {
  return __builtin_amdgcn_rcpf(1.f + fexp(-x));
}
__device__ __forceinline__ float ftanh(float x) {
  return 1.f - 2.f * __builtin_amdgcn_rcpf(fexp(2.f * x) + 1.f);
}

// ---------------------------------------------------------------- conversions
__global__ void k_split3(const float* __restrict__ src, __bf16* __restrict__ hi,
                         __bf16* __restrict__ mid, __bf16* __restrict__ lo, int n4) {
  int i = blockIdx.x * 256 + threadIdx.x;
  if (i >= n4) return;
  f32x4 v = ((const f32x4*)src)[i];
  bf16x4 h, m, l;
#pragma unroll
  for (int j = 0; j < 4; ++j) {
    float x = v[j];
    __bf16 hb = (__bf16)x;
    float r1 = x - (float)hb;
    __bf16 mb = (__bf16)r1;
    float r2 = r1 - (float)mb;
    h[j] = hb; m[j] = mb; l[j] = (__bf16)r2;
  }
  ((bf16x4*)hi)[i] = h; ((bf16x4*)mid)[i] = m; ((bf16x4*)lo)[i] = l;
}

// fallback-path single-matrix convert
__global__ void k_cvt1(const float* __restrict__ src, __bf16* __restrict__ dst, int n4) {
  int i = blockIdx.x * 256 + threadIdx.x;
  if (i >= n4) return;
  f32x4 v = ((const f32x4*)src)[i];
  bf16x4 o;
#pragma unroll
  for (int j = 0; j < 4; ++j) o[j] = (__bf16)v[j];
  ((bf16x4*)dst)[i] = o;
}

// ---------------------------------------------------------------- gi GEMM
__global__ __launch_bounds__(256, 2)
void k_gemm_gi(const __bf16* __restrict__ xh, const __bf16* __restrict__ xm,
               const __bf16* __restrict__ xl, const __bf16* __restrict__ wh,
               const __bf16* __restrict__ wm, const __bf16* __restrict__ wl,
               const float* __restrict__ bih, float* __restrict__ gi) {
  __shared__ __bf16 sA[128 * 64], sB[128 * 64];
  const int t = threadIdx.x;
  const int m0 = blockIdx.x * 128, n0 = blockIdx.y * 128;
  f32x4 acc[4][4] = {};
  const __bf16* As[6] = {xh, xh, xm, xh, xm, xl};
  const __bf16* Bs[6] = {wh, wm, wh, wl, wm, wh};
  for (int p = 0; p < 6; ++p) {
    const __bf16* A = As[p];
    const __bf16* Bm = Bs[p];
    for (int kt = 0; kt < D_ / 64; ++kt) {
      __syncthreads();
      stage128x64(sA, A + (size_t)m0 * D_ + kt * 64, D_, t);
      stage128x64(sB, Bm + (size_t)n0 * D_ + kt * 64, D_, t);
      __syncthreads();
      mfma_tile(sA, sB, acc, t);
    }
  }
  const int w = t >> 6, l = t & 63, wr = w >> 1, wc = w & 1;
  const int col = l & 15, rb = (l >> 4) * 4;
#pragma unroll
  for (int m = 0; m < 4; ++m)
#pragma unroll
    for (int n = 0; n < 4; ++n)
#pragma unroll
      for (int i = 0; i < 4; ++i) {
        int gm = m0 + 64 * wr + 16 * m + rb + i;
        int gn = n0 + 64 * wc + 16 * n + col;
        gi[(size_t)gm * 768 + gn] = acc[m][n][i] + bih[gn];
      }
}

// ---------------------------------------------------------------- FUSED kernel
// blocks [0,16): phase-overlapped scan. blocks [16,16+nGemm): dense gate-up
// for all 8 experts (hidden under the scan). rest: Wd f32->bf16 convert.
// Scan phase structure per step: [B: remote-col partials from hbuf[cur]] ->
// reduce/activations/h -> store own h -> barrier1 -> {pollers fetch partner h
// || own-col threads compute NEXT step's own-half partials} -> barrier2.
// The LLC poll RT hides under the own-half weight stream.
__global__ __attribute__((amdgpu_flat_work_group_size(512, 512)))
__attribute__((amdgpu_waves_per_eu(2, 2)))
void k_fused(const float* __restrict__ Whh, const float* __restrict__ gi,
             const float* __restrict__ bhh, float* __restrict__ hs,
             float* __restrict__ newh,
             const __bf16* __restrict__ xbf, const float* __restrict__ Wg,
             const float* __restrict__ Wu, __bf16* __restrict__ Hall,
             const float* __restrict__ Wd, __bf16* __restrict__ Wdbf,
             int nGemm) {
  __shared__ __align__(16) char smem[98304];
  const int bid = blockIdx.x;

  if (bid < 16) {
    // -------- scan path (phase-overlapped exchange) --------
    int role;
    switch (bid) {
      case 0: role = 0; break;
      case 8: role = 1; break;
      case 1: role = 2; break;
      case 9: role = 3; break;
      default: return;
    }
    const int b = role >> 1, half = role & 1;
    const int t = threadIdx.x;
    const int c = t & 3;                 // col slice: h[64c..64c+63]
    const int q = t >> 2;                // local unit 0..127
    const int g = half * 128 + q;        // owned global unit
    const bool isOwn = ((c >> 1) == half);       // slice within own half
    const bool isPoller = (c == 2 * (half ^ 1)); // 128 threads
    const int pg = (half ^ 1) * 128 + q;         // polled partner unit
    float (*hbuf)[256] = (float(*)[256])smem;

    f32x2 w0[32], w1[32], w2[32];
#pragma unroll
    for (int j = 0; j < 16; ++j) {
      const int jr = (j + 2 * c) & 15;
      const size_t colo = (size_t)(64 * c + 4 * jr);
      f32x4 v0 = *(const f32x4*)(Whh + (size_t)g * 256 + colo);
      f32x4 v1 = *(const f32x4*)(Whh + (size_t)(g + 256) * 256 + colo);
      f32x4 v2 = *(const f32x4*)(Whh + (size_t)(g + 512) * 256 + colo);
      w0[2 * j] = f32x2{v0[0], v0[1]}; w0[2 * j + 1] = f32x2{v0[2], v0[3]};
      w1[2 * j] = f32x2{v1[0], v1[1]}; w1[2 * j + 1] = f32x2{v1[2], v1[3]};
      w2[2 * j] = f32x2{v2[0], v2[1]}; w2[2 * j + 1] = f32x2{v2[2], v2[3]};
    }
#pragma unroll
    for (int j = 0; j < 32; ++j) {
      asm("" : "+v"(w0[j]));
      asm("" : "+v"(w1[j]));
      asm("" : "+v"(w2[j]));
    }
    const float bh0 = bhh[g], bh1 = bhh[g + 256], bh2 = bhh[g + 512];
    if (t < 256) { hbuf[0][t] = 0.f; }
    float h_old = 0.f;
    const float* giB = gi + (size_t)(b * S_) * 768;
    float* hsB = hs + (size_t)b * 256;
    float ir = giB[g], iz = giB[g + 256], in_ = giB[g + 512];
    // carried partials: own-col threads fill these in phase C; start at 0
    // (h before step 0 is 0, so both own and remote partials are 0).
    f32x2 a0 = {0.f, 0.f}, a1 = a0, a2 = a0;
    __syncthreads();

    for (int s = 0; s < S_; ++s) {
      const int cur = s & 1, nxt = cur ^ 1;
      const int sn = (s + 1 < S_) ? s + 1 : s;
      const float irn = giB[(size_t)sn * 768 + g];
      const float izn = giB[(size_t)sn * 768 + g + 256];
      const float inn = giB[(size_t)sn * 768 + g + 512];

      // phase B: remote-col threads accumulate from hbuf[cur] (partner h,
      // fetched by pollers during the previous step's C window)
      if (!isOwn) {
#pragma unroll
        for (int j = 0; j < 16; ++j) {
          const int jr = (j + 2 * c) & 15;
          f32x4 hv = *(const f32x4*)&hbuf[cur][64 * c + 4 * jr];
          f32x2 hA = {hv[0], hv[1]}, hB = {hv[2], hv[3]};
          a0 = pkfma(w0[2 * j], hA, a0); a0 = pkfma(w0[2 * j + 1], hB, a0);
          a1 = pkfma(w1[2 * j], hA, a1); a1 = pkfma(w1[2 * j + 1], hB, a1);
          a2 = pkfma(w2[2 * j], hA, a2); a2 = pkfma(w2[2 * j + 1], hB, a2);
        }
      }
      float d0 = (a0[0] + a0[1]);
      float d1 = (a1[0] + a1[1]);
      float d2 = (a2[0] + a2[1]);
      d0 += __shfl_xor(d0, 1); d0 += __shfl_xor(d0, 2);
      d1 += __shfl_xor(d1, 1); d1 += __shfl_xor(d1, 2);
      d2 += __shfl_xor(d2, 1); d2 += __shfl_xor(d2, 2);

      const float r = fsig(ir + d0 + bh0);
      const float z = fsig(iz + d1 + bh1);
      const float n = ftanh(in_ + r * (d2 + bh2));
      const float hn = (1.f - z) * n + z * h_old;
      h_old = hn;
      a0 = f32x2{0.f, 0.f}; a1 = a0; a2 = a0;   // reset partials

      float* hsrow = hsB + (size_t)s * 512;
      if (c == 0) {
        hbuf[nxt][g] = hn;
        __hip_atomic_store(hsrow + g, hn, __ATOMIC_RELAXED, __HIP_MEMORY_SCOPE_AGENT);
        if (s == S_ - 1) newh[b * 256 + g] = hn;
      }
      __syncthreads();   // barrier1: own h(s) visible in hbuf[nxt]

      // phase C: own-col threads compute next step's own-half partials
      // WHILE pollers fetch the partner's h(s) (LLC RT hides under the stream)
      if (isPoller) {
        float v;
        do {
          v = __hip_atomic_load(hsrow + pg, __ATOMIC_RELAXED, __HIP_MEMORY_SCOPE_AGENT);
        } while (v != v);              // NaN-poisoned until written
        hbuf[nxt][pg] = v;
      }
      if (isOwn) {
#pragma unroll
        for (int j = 0; j < 16; ++j) {
          const int jr = (j + 2 * c) & 15;
          f32x4 hv = *(const f32x4*)&hbuf[nxt][64 * c + 4 * jr];
          f32x2 hA = {hv[0], hv[1]}, hB = {hv[2], hv[3]};
          a0 = pkfma(w0[2 * j], hA, a0); a0 = pkfma(w0[2 * j + 1], hB, a0);
          a1 = pkfma(w1[2 * j], hA, a1); a1 = pkfma(w1[2 * j + 1], hB, a1);
          a2 = pkfma(w2[2 * j], hA, a2); a2 = pkfma(w2[2 * j + 1], hB, a2);
        }
      }
      ir = irn; iz = izn; in_ = inn;
      __syncthreads();   // barrier2: partner h(s) visible for next phase B
    }

  } else if (bid < 16 + nGemm) {
    // -------- dense gate-up path (all experts, hidden under the scan) --------
    const int bi = bid - 16;
    const int e = bi >> 10, r = bi & 1023;      // 1024 = 32x32 tiles per expert
    const int m0 = (r & 31) * 128, n0 = (r >> 5) * 128;
    __bf16* sA = (__bf16*)smem;
    __bf16* sB = sA + 128 * 64;
    __bf16* sC = sB + 128 * 64;
    const int t = threadIdx.x;
    const float* wg = Wg + (size_t)e * HH_ * D_;
    const float* wu = Wu + (size_t)e * HH_ * D_;
    f32x4 ag[4][4] = {}, au[4][4] = {};
    for (int kt = 0; kt < D_ / 64; ++kt) {
      __syncthreads();
      if (t < 256) {
        stage128x64(sA, xbf + (size_t)m0 * D_ + kt * 64, D_, t);
        stage128x64_cvt(sB, wg + (size_t)n0 * D_ + kt * 64, D_, t);
        stage128x64_cvt(sC, wu + (size_t)n0 * D_ + kt * 64, D_, t);
      }
      __syncthreads();
      if (t < 256) mfma_tile2(sA, sB, sC, ag, au, t);
    }
    if (t < 256) {
      const int w = t >> 6, l = t & 63, wr = w >> 1, wc = w & 1;
      const int col = l & 15, rb = (l >> 4) * 4;
#pragma unroll
      for (int m = 0; m < 4; ++m)
#pragma unroll
        for (int n = 0; n < 4; ++n)
#pragma unroll
          for (int i = 0; i < 4; ++i) {
            int gm = m0 + 64 * wr + 16 * m + rb + i;    // token index
            int gn = n0 + 64 * wc + 16 * n + col;
            float gv = ag[m][n][i], uv = au[m][n][i];
            float h = 0.5f * gv * (1.f + erff(gv * 0.70710678118654752440f)) * uv;
            Hall[((size_t)e * 4096 + gm) * HH_ + gn] = (__bf16)h;
          }
    }

  } else {
    // -------- Wd f32->bf16 convert path --------
    const int bi2 = bid - 16 - nGemm;
    const size_t base = (size_t)bi2 * 512 + threadIdx.x;
#pragma unroll
    for (int k2 = 0; k2 < 4; ++k2) {
      const size_t u = base + (size_t)k2 * 2097152;  // f32x4 units, 8.39M total
      f32x4 v = ((const f32x4*)Wd)[u];
      bf16x4 o;
#pragma unroll
      for (int j = 0; j < 4; ++j) o[j] = (__bf16)v[j];
      ((bf16x4*)Wdbf)[u] = o;
    }
  }
}

// ---------------------------------------------------------------- router (logits+finish+build)
__global__ void k_router(const float* __restrict__ hs, const float* __restrict__ Wr,
                         const float* __restrict__ br, float* __restrict__ logits,
                         float* __restrict__ wdense, int* __restrict__ cnt,
                         int* __restrict__ list, float* __restrict__ partials) {
  const int tok = blockIdx.x * 256 + threadIdx.x;  // 4096
  const int s = tok & (S_ - 1), b = tok >> 11;
  const f32x4* h4 = (const f32x4*)&hs[((size_t)s * 2 + b) * 256];
  float p[8];
  float mx = -1e30f;
#pragma unroll
  for (int e = 0; e < 8; ++e) {
    const f32x4* w4 = (const f32x4*)&Wr[e * 256];
    float acc = 0.f;
#pragma unroll 8
    for (int k = 0; k < 64; ++k) {
      f32x4 a = h4[k], w = w4[k];
      acc += a[0] * w[0] + a[1] * w[1] + a[2] * w[2] + a[3] * w[3];
    }
    acc += br[e];
    logits[tok * 8 + e] = acc;
    p[e] = acc;
    mx = fmaxf(mx, acc);
  }
  float sum = 0.f;
#pragma unroll
  for (int e = 0; e < 8; ++e) { p[e] = expf(p[e] - mx); sum += p[e]; }
  const float inv = 1.f / sum;
#pragma unroll
  for (int e = 0; e < 8; ++e) p[e] *= inv;
  int i1 = 0;
#pragma unroll
  for (int e = 1; e < 8; ++e) if (p[e] > p[i1]) i1 = e;   // ties -> lower index
  int i2 = -1; float p2 = -1.f;
#pragma unroll
  for (int e = 0; e < 8; ++e) if (e != i1 && p[e] > p2) { p2 = p[e]; i2 = e; }
  const float inv2 = 1.f / (p[i1] + p2);
#pragma unroll
  for (int e = 0; e < 8; ++e)
    wdense[tok * 8 + e] = (e == i1) ? p[i1] * inv2 : (e == i2 ? p2 * inv2 : 0.f);
  // build routing lists (atomic order varies; per-token once per expert ->
  // position-independent row results -> deterministic output)
  {
    int pos = atomicAdd(&cnt[i1], 1);
    list[i1 * 4096 + pos] = tok;
    pos = atomicAdd(&cnt[i2], 1);
    list[i2 * 4096 + pos] = tok;
  }

  __shared__ float ps[256][8];
#pragma unroll
  for (int e = 0; e < 8; ++e) ps[threadIdx.x][e] = p[e];
  __syncthreads();
  for (int st = 128; st >= 1; st >>= 1) {
    if (threadIdx.x < st)
#pragma unroll
      for (int e = 0; e < 8; ++e) ps[threadIdx.x][e] += ps[threadIdx.x + st][e];
    __syncthreads();
  }
  if (threadIdx.x == 0)
#pragma unroll
    for (int e = 0; e < 8; ++e) partials[blockIdx.x * 8 + e] = ps[0][e];
}

__global__ void k_aux(const float* __restrict__ partials, float* __restrict__ aux) {
  __shared__ float m2[8];
  const int e = threadIdx.x;
  if (e < 8) {
    float s = 0.f;
    for (int bl = 0; bl < 16; ++bl) s += partials[bl * 8 + e];
    const float mean = s / 4096.f;
    m2[e] = mean * mean;
  }
  __syncthreads();
  if (threadIdx.x == 0) {
    float s = 0.f;
#pragma unroll
    for (int i = 0; i < 8; ++i) s += m2[i];
    aux[0] = 8.f * s;
  }
}

// ---------------------------------------------------------------- fallback dense gate-up
__global__ __launch_bounds__(256, 2)
void k_gateup_d(const __bf16* __restrict__ xbf, const float* __restrict__ Wg,
                const float* __restrict__ Wu, __bf16* __restrict__ Hout) {
  __shared__ __bf16 sA[128 * 64], sB[128 * 64], sC[128 * 64];
  const int t = threadIdx.x;
  const int m0 = blockIdx.x * 128, n0 = blockIdx.y * 128;
  f32x4 ag[4][4] = {}, au[4][4] = {};
  for (int kt = 0; kt < D_ / 64; ++kt) {
    __syncthreads();
    stage128x64(sA, xbf + (size_t)m0 * D_ + kt * 64, D_, t);
    stage128x64_cvt(sB, Wg + (size_t)n0 * D_ + kt * 64, D_, t);
    stage128x64_cvt(sC, Wu + (size_t)n0 * D_ + kt * 64, D_, t);
    __syncthreads();
    mfma_tile2(sA, sB, sC, ag, au, t);
  }
  const int w = t >> 6, l = t & 63, wr = w >> 1, wc = w & 1;
  const int col = l & 15, rb = (l >> 4) * 4;
#pragma unroll
  for (int m = 0; m < 4; ++m)
#pragma unroll
    for (int n = 0; n < 4; ++n)
#pragma unroll
      for (int i = 0; i < 4; ++i) {
        int gm = m0 + 64 * wr + 16 * m + rb + i;
        int gn = n0 + 64 * wc + 16 * n + col;
        float gv = ag[m][n][i], uv = au[m][n][i];
        float h = 0.5f * gv * (1.f + erff(gv * 0.70710678118654752440f)) * uv;
        Hout[(size_t)gm * HH_ + gn] = (__bf16)h;
      }
}

// ---------------------------------------------------------------- sparse down
// z-batched over experts; atomic out accumulation (two experts per token run
// concurrently). out starts 0, exactly 2 commutative float adds per element.
__global__ __launch_bounds__(256, 2)
void k_down_s(const __bf16* __restrict__ Hbase, const __bf16* __restrict__ Wdbase,
              const float* __restrict__ wdense, const int* __restrict__ list,
              const int* __restrict__ cnt, float* __restrict__ out,
              int eBase, int hRowsPerE, long long wStridePerE) {
  __shared__ __bf16 sA[128 * 64], sB[128 * 64];
  __shared__ int rowtok[128];
  const int e = eBase + blockIdx.z;
  const int t = threadIdx.x;
  const int m0 = blockIdx.x * 128, n0 = blockIdx.y * 128;
  const int ce = cnt[e];
  if (m0 >= ce) return;
  if (t < 128) rowtok[t] = list[e * 4096 + m0 + t];
  const __bf16* Hrows = Hbase + (size_t)e * hRowsPerE * HH_;
  const __bf16* Wde = Wdbase + (size_t)e * (size_t)wStridePerE;
  f32x4 acc[4][4] = {};
  for (int kt = 0; kt < HH_ / 64; ++kt) {
    __syncthreads();
    stage128x64_gather(sA, Hrows, HH_, kt * 64, rowtok, t);
    stage128x64(sB, Wde + (size_t)n0 * HH_ + kt * 64, HH_, t);
    __syncthreads();
    mfma_tile(sA, sB, acc, t);
  }
  const int w = t >> 6, l = t & 63, wr = w >> 1, wc = w & 1;
  const int col = l & 15, rb = (l >> 4) * 4;
#pragma unroll
  for (int m = 0; m < 4; ++m)
#pragma unroll
    for (int i = 0; i < 4; ++i) {
      const int lr = 64 * wr + 16 * m + rb + i;
      if (m0 + lr < ce) {
        const int tok = rowtok[lr];
        const float wv = wdense[tok * 8 + e];
#pragma unroll
        for (int n = 0; n < 4; ++n) {
          const int gn = n0 + 64 * wc + 16 * n + col;
          atomicAdd(&out[(size_t)tok * 1024 + gn], wv * acc[m][n][i]);
        }
      }
    }
}

// ---------------------------------------------------------------- launch
extern "C" void kernel_launch(void* const* d_in, const int* in_sizes, int n_in,
                              void* d_out, int out_size, void* d_ws, size_t ws_size,
                              hipStream_t stream) {
  (void)in_sizes; (void)n_in; (void)out_size;
  const float* x    = (const float*)d_in[0];
  const float* Wg   = (const float*)d_in[1];
  const float* Wu   = (const float*)d_in[2];
  const float* Wd   = (const float*)d_in[3];
  const float* Wih  = (const float*)d_in[4];
  const float* Whh  = (const float*)d_in[5];
  const float* bih  = (const float*)d_in[6];
  const float* bhh  = (const float*)d_in[7];
  const float* Wr   = (const float*)d_in[8];
  const float* br   = (const float*)d_in[9];

  float* out    = (float*)d_out;                       // (B,S,D)
  float* logits = out + (size_t)B_ * S_ * D_;          // (B,S,E)
  float* newh   = logits + (size_t)B_ * S_ * E_;       // (B,RH)
  float* aux    = newh + (size_t)B_ * RH_;             // scalar

  char* ws = (char*)d_ws;
  size_t off = 0;
  auto alloc = [&](size_t bytes) { size_t r = off; off += (bytes + 255) & ~(size_t)255; return r; };
  const size_t XN = (size_t)B_ * S_ * D_;              // 4,194,304
  const size_t WIN = (size_t)3 * RH_ * D_;             // 786,432

  // ---- common buffers ----
  __bf16* xh  = (__bf16*)(ws + alloc(XN * 2));
  __bf16* xm  = (__bf16*)(ws + alloc(XN * 2));
  __bf16* xl  = (__bf16*)(ws + alloc(XN * 2));
  __bf16* wih_h = (__bf16*)(ws + alloc(WIN * 2));
  __bf16* wih_m = (__bf16*)(ws + alloc(WIN * 2));
  __bf16* wih_l = (__bf16*)(ws + alloc(WIN * 2));
  float*  gi  = (float*)(ws + alloc((size_t)B_ * S_ * 768 * 4));
  float*  hs  = (float*)(ws + alloc((size_t)S_ * B_ * RH_ * 4));
  float*  wdense = (float*)(ws + alloc((size_t)B_ * S_ * E_ * 4));
  int*    cnt  = (int*)(ws + alloc(E_ * 4));
  int*    list = (int*)(ws + alloc((size_t)E_ * 4096 * 4));
  float*  partials = (float*)(ws + alloc(16 * 8 * 4));
  const size_t commonEnd = off;

  // fused-path sizes
  const size_t szWdbfAll = (size_t)E_ * D_ * HH_ * 2;      // 67 MB
  const size_t szHall    = (size_t)E_ * 4096 * HH_ * 2;    // 268 MB
  const bool fused = (commonEnd + szWdbfAll + szHall + 512) <= ws_size;

  hipMemsetAsync(out, 0, XN * 4, stream);
  hipMemsetAsync(hs, 0xFF, (size_t)S_ * B_ * RH_ * 4, stream);  // NaN-poison
  hipMemsetAsync(cnt, 0, E_ * 4, stream);
  hipMemsetAsync(list, 0, (size_t)E_ * 4096 * 4, stream);

  k_split3<<<dim3((XN / 4 + 255) / 256), 256, 0, stream>>>(x, xh, xm, xl, (int)(XN / 4));
  k_split3<<<dim3((WIN / 4 + 255) / 256), 256, 0, stream>>>(Wih, wih_h, wih_m, wih_l, (int)(WIN / 4));
  k_gemm_gi<<<dim3(32, 6), 256, 0, stream>>>(xh, xm, xl, wih_h, wih_m, wih_l, bih, gi);

  if (fused) {
    __bf16* WdbfA = (__bf16*)(ws + alloc(szWdbfAll));
    __bf16* Hall  = (__bf16*)(ws + alloc(szHall));
    const int nGemm = E_ * 32 * 32;      // 8192
    const int nCvt  = 4096;
    // scan || dense gate-up (all experts) || Wd convert — one launch
    k_fused<<<dim3(16 + nGemm + nCvt), 512, 0, stream>>>(
        Whh, gi, bhh, hs, newh, xh, Wg, Wu, Hall, Wd, WdbfA, nGemm);
    k_router<<<dim3(16), 256, 0, stream>>>(hs, Wr, br, logits, wdense, cnt, list, partials);
    k_aux<<<dim3(1), 64, 0, stream>>>(partials, aux);
    // sparse down for all experts in one z-batched launch (atomic scatter-add)
    k_down_s<<<dim3(32, 8, 8), 256, 0, stream>>>(
        Hall, WdbfA, wdense, list, cnt, out, 0, 4096, (long long)D_ * HH_);
  } else {
    __bf16* Wdbf = (__bf16*)(ws + alloc((size_t)D_ * HH_ * 2));
    __bf16* Htmp = (__bf16*)(ws + alloc((size_t)B_ * S_ * HH_ * 2));
    // scan only (fused kernel with grid=16 runs just the scan roles)
    k_fused<<<dim3(16), 512, 0, stream>>>(
        Whh, gi, bhh, hs, newh, xh, Wg, Wu, Htmp, Wd, Wdbf, 0);
    k_router<<<dim3(16), 256, 0, stream>>>(hs, Wr, br, logits, wdense, cnt, list, partials);
    k_aux<<<dim3(1), 64, 0, stream>>>(partials, aux);
    const int n4w = (int)((size_t)HH_ * D_ / 4);
    for (int e = 0; e < E_; ++e) {
      const size_t wo = (size_t)e * HH_ * D_;
      k_cvt1<<<dim3((n4w + 255) / 256), 256, 0, stream>>>(Wd + wo, Wdbf, n4w);
      k_gateup_d<<<dim3(32, 32), 256, 0, stream>>>(xh, Wg + wo, Wu + wo, Htmp);
      k_down_s<<<dim3(32, 8, 1), 256, 0, stream>>>(
          Htmp, Wdbf, wdense, list, cnt, out, e, 0, 0);
    }
  }
}

// Round 17
// 3279.346 us; speedup vs baseline: 1.3707x; 1.3707x over previous
//
#include <hip/hip_runtime.h>
#include <cstdint>
#include <cstddef>

#define B_  2
#define S_  2048
#define D_  1024
#define HH_ 4096
#define E_  8
#define RH_ 256

typedef float  f32x4 __attribute__((ext_vector_type(4)));
typedef float  f32x2 __attribute__((ext_vector_type(2)));
typedef __bf16 bf16x8 __attribute__((ext_vector_type(8)));
typedef __bf16 bf16x4 __attribute__((ext_vector_type(4)));

// ---------------------------------------------------------------- helpers
__device__ __forceinline__ void gload_lds16(const void* g, void* l) {
  __builtin_amdgcn_global_load_lds(
      (const __attribute__((address_space(1))) unsigned int*)g,
      (__attribute__((address_space(3))) unsigned int*)l, 16, 0, 0);
}

// stage a 128x64 bf16 tile (row-major, leading dim ldK elems) into LDS linearly
__device__ __forceinline__ void stage128x64(__bf16* s, const __bf16* g, int ldK, int t) {
  const int wv = t >> 6, l = t & 63;
#pragma unroll
  for (int p = 0; p < 4; ++p) {
    const int base = p * 256 + wv * 64;      // wave-uniform flat base
    const int flat = base + l;               // per-lane
    const int row = flat >> 3, c16 = flat & 7;
    gload_lds16(g + (size_t)row * ldK + c16 * 8, s + (size_t)base * 8);
  }
}

// stage a 128x64 tile from F32 source, converting to bf16 (RNE) via registers
__device__ __forceinline__ void stage128x64_cvt(__bf16* s, const float* g, int ldK, int t) {
#pragma unroll
  for (int p = 0; p < 4; ++p) {
    const int flat = p * 256 + t;
    const int row = flat >> 3, c8 = (flat & 7) << 3;
    const float* src = g + (size_t)row * ldK + c8;
    f32x4 a = *(const f32x4*)src;
    f32x4 b = *(const f32x4*)(src + 4);
    bf16x8 o;
#pragma unroll
    for (int j2 = 0; j2 < 4; ++j2) { o[j2] = (__bf16)a[j2]; o[4 + j2] = (__bf16)b[j2]; }
    *(bf16x8*)&s[(size_t)flat * 8] = o;
  }
}

// gather-stage: row r of the tile comes from src row rowtok[r]
__device__ __forceinline__ void stage128x64_gather(__bf16* s, const __bf16* src,
                                                   int ldK, int k0,
                                                   const int* rowtok, int t) {
  const int wv = t >> 6, l = t & 63;
#pragma unroll
  for (int p = 0; p < 4; ++p) {
    const int base = p * 256 + wv * 64;
    const int flat = base + l;
    const int row = flat >> 3, c16 = flat & 7;
    const int tok = rowtok[row];
    gload_lds16(src + (size_t)tok * ldK + k0 + c16 * 8, s + (size_t)base * 8);
  }
}

__device__ __forceinline__ void mfma_tile(const __bf16* sA, const __bf16* sB,
                                          f32x4 acc[4][4], int t) {
  const int w = t >> 6, l = t & 63;
  const int wr = w >> 1, wc = w & 1;
  const int fr = l & 15, fk = (l >> 4) * 8;
#pragma unroll
  for (int kk = 0; kk < 2; ++kk) {
    bf16x8 a[4], b[4];
#pragma unroll
    for (int m = 0; m < 4; ++m)
      a[m] = *(const bf16x8*)&sA[(64 * wr + 16 * m + fr) * 64 + kk * 32 + fk];
#pragma unroll
    for (int n = 0; n < 4; ++n)
      b[n] = *(const bf16x8*)&sB[(64 * wc + 16 * n + fr) * 64 + kk * 32 + fk];
#pragma unroll
    for (int m = 0; m < 4; ++m)
#pragma unroll
      for (int n = 0; n < 4; ++n)
        acc[m][n] = __builtin_amdgcn_mfma_f32_16x16x32_bf16(a[m], b[n], acc[m][n], 0, 0, 0);
  }
}

__device__ __forceinline__ void mfma_tile2(const __bf16* sA, const __bf16* sB,
                                           const __bf16* sC, f32x4 accg[4][4],
                                           f32x4 accu[4][4], int t) {
  const int w = t >> 6, l = t & 63;
  const int wr = w >> 1, wc = w & 1;
  const int fr = l & 15, fk = (l >> 4) * 8;
#pragma unroll
  for (int kk = 0; kk < 2; ++kk) {
    bf16x8 a[4], bg[4], bu[4];
#pragma unroll
    for (int m = 0; m < 4; ++m)
      a[m] = *(const bf16x8*)&sA[(64 * wr + 16 * m + fr) * 64 + kk * 32 + fk];
#pragma unroll
    for (int n = 0; n < 4; ++n) {
      bg[n] = *(const bf16x8*)&sB[(64 * wc + 16 * n + fr) * 64 + kk * 32 + fk];
      bu[n] = *(const bf16x8*)&sC[(64 * wc + 16 * n + fr) * 64 + kk * 32 + fk];
    }
#pragma unroll
    for (int m = 0; m < 4; ++m)
#pragma unroll
      for (int n = 0; n < 4; ++n) {
        accg[m][n] = __builtin_amdgcn_mfma_f32_16x16x32_bf16(a[m], bg[n], accg[m][n], 0, 0, 0);
        accu[m][n] = __builtin_amdgcn_mfma_f32_16x16x32_bf16(a[m], bu[n], accu[m][n], 0, 0, 0);
      }
  }
}

// packed f32 FMA: d = a*b + d
__device__ __forceinline__ f32x2 pkfma(f32x2 a, f32x2 b, f32x2 d) {
  asm("v_pk_fma_f32 %0, %1, %2, %0" : "+v"(d) : "v"(a), "v"(b));
  return d;
}

// inline HW transcendentals (no libm calls in the scan)
__device__ __forceinline__ float fexp(float x) {
  return __builtin_amdgcn_exp2f(x * 1.44269504088896f);
}
__device__ __forceinline__ float fsig(float x) {
  return __builtin_amdgcn_rcpf(1.f + fexp(-x));
}
__device__ __forceinline__ float ftanh(float x) {
  return 1.f - 2.f * __builtin_amdgcn_rcpf(fexp(2.f * x) + 1.f);
}

// ---------------------------------------------------------------- conversions
__global__ void k_split3(const float* __restrict__ src, __bf16* __restrict__ hi,
                         __bf16* __restrict__ mid, __bf16* __restrict__ lo, int n4) {
  int i = blockIdx.x * 256 + threadIdx.x;
  if (i >= n4) return;
  f32x4 v = ((const f32x4*)src)[i];
  bf16x4 h, m, l;
#pragma unroll
  for (int j = 0; j < 4; ++j) {
    float x = v[j];
    __bf16 hb = (__bf16)x;
    float r1 = x - (float)hb;
    __bf16 mb = (__bf16)r1;
    float r2 = r1 - (float)mb;
    h[j] = hb; m[j] = mb; l[j] = (__bf16)r2;
  }
  ((bf16x4*)hi)[i] = h; ((bf16x4*)mid)[i] = m; ((bf16x4*)lo)[i] = l;
}

// fallback-path single-matrix convert
__global__ void k_cvt1(const float* __restrict__ src, __bf16* __restrict__ dst, int n4) {
  int i = blockIdx.x * 256 + threadIdx.x;
  if (i >= n4) return;
  f32x4 v = ((const f32x4*)src)[i];
  bf16x4 o;
#pragma unroll
  for (int j = 0; j < 4; ++j) o[j] = (__bf16)v[j];
  ((bf16x4*)dst)[i] = o;
}

// ---------------------------------------------------------------- gi GEMM
// 6-buffer single staging: per K-tile stage all 3 A-splits + 3 B-splits once
// (96 KB LDS) and issue the 6 split products from it. Halves staging traffic
// vs the 6-pass version. Accumulation-order change across products only
// (~1e-7 relative - harmless).
__global__ __launch_bounds__(256, 1)
void k_gemm_gi(const __bf16* __restrict__ xh, const __bf16* __restrict__ xm,
               const __bf16* __restrict__ xl, const __bf16* __restrict__ wh,
               const __bf16* __restrict__ wm, const __bf16* __restrict__ wl,
               const float* __restrict__ bih, float* __restrict__ gi) {
  __shared__ __bf16 sA[3][128 * 64], sB[3][128 * 64];
  const int t = threadIdx.x;
  const int m0 = blockIdx.x * 128, n0 = blockIdx.y * 128;
  f32x4 acc[4][4] = {};
  for (int kt = 0; kt < D_ / 64; ++kt) {
    __syncthreads();
    stage128x64(sA[0], xh + (size_t)m0 * D_ + kt * 64, D_, t);
    stage128x64(sA[1], xm + (size_t)m0 * D_ + kt * 64, D_, t);
    stage128x64(sA[2], xl + (size_t)m0 * D_ + kt * 64, D_, t);
    stage128x64(sB[0], wh + (size_t)n0 * D_ + kt * 64, D_, t);
    stage128x64(sB[1], wm + (size_t)n0 * D_ + kt * 64, D_, t);
    stage128x64(sB[2], wl + (size_t)n0 * D_ + kt * 64, D_, t);
    __syncthreads();
    mfma_tile(sA[0], sB[0], acc, t);   // h*h
    mfma_tile(sA[0], sB[1], acc, t);   // h*m
    mfma_tile(sA[1], sB[0], acc, t);   // m*h
    mfma_tile(sA[0], sB[2], acc, t);   // h*l
    mfma_tile(sA[1], sB[1], acc, t);   // m*m
    mfma_tile(sA[2], sB[0], acc, t);   // l*h
  }
  const int w = t >> 6, l = t & 63, wr = w >> 1, wc = w & 1;
  const int col = l & 15, rb = (l >> 4) * 4;
#pragma unroll
  for (int m = 0; m < 4; ++m)
#pragma unroll
    for (int n = 0; n < 4; ++n)
#pragma unroll
      for (int i = 0; i < 4; ++i) {
        int gm = m0 + 64 * wr + 16 * m + rb + i;
        int gn = n0 + 64 * wc + 16 * n + col;
        gi[(size_t)gm * 768 + gn] = acc[m][n][i] + bih[gn];
      }
}

// ---------------------------------------------------------------- FUSED kernel
// blocks [0,16): r11 scan VERBATIM (r15-measured: fused 2874us). blocks
// [16,16+nGemm): dense gate-up for all 8 experts (hidden under the scan).
// rest: Wd f32->bf16 convert. 96KB static LDS => 1 block/CU.
__global__ __attribute__((amdgpu_flat_work_group_size(512, 512)))
__attribute__((amdgpu_waves_per_eu(2, 2)))
void k_fused(const float* __restrict__ Whh, const float* __restrict__ gi,
             const float* __restrict__ bhh, float* __restrict__ hs,
             float* __restrict__ newh,
             const __bf16* __restrict__ xbf, const float* __restrict__ Wg,
             const float* __restrict__ Wu, __bf16* __restrict__ Hall,
             const float* __restrict__ Wd, __bf16* __restrict__ Wdbf,
             int nGemm) {
  __shared__ __align__(16) char smem[98304];
  const int bid = blockIdx.x;

  if (bid < 16) {
    // -------- scan path (r11 verbatim; r16's phase-overlap REVERTED: it
    // halved active threads per phase and doubled the weight-stream time) ----
    int role;
    switch (bid) {
      case 0: role = 0; break;
      case 8: role = 1; break;
      case 1: role = 2; break;
      case 9: role = 3; break;
      default: return;
    }
    const int b = role >> 1, half = role & 1;
    const int t = threadIdx.x;
    const int c = t & 3;
    const int q = t >> 2;
    const int g = half * 128 + q;
    float (*hbuf)[256] = (float(*)[256])smem;

    f32x2 w0[32], w1[32], w2[32];
#pragma unroll
    for (int j = 0; j < 16; ++j) {
      const int jr = (j + 2 * c) & 15;
      const size_t colo = (size_t)(64 * c + 4 * jr);
      f32x4 v0 = *(const f32x4*)(Whh + (size_t)g * 256 + colo);
      f32x4 v1 = *(const f32x4*)(Whh + (size_t)(g + 256) * 256 + colo);
      f32x4 v2 = *(const f32x4*)(Whh + (size_t)(g + 512) * 256 + colo);
      w0[2 * j] = f32x2{v0[0], v0[1]}; w0[2 * j + 1] = f32x2{v0[2], v0[3]};
      w1[2 * j] = f32x2{v1[0], v1[1]}; w1[2 * j + 1] = f32x2{v1[2], v1[3]};
      w2[2 * j] = f32x2{v2[0], v2[1]}; w2[2 * j + 1] = f32x2{v2[2], v2[3]};
    }
#pragma unroll
    for (int j = 0; j < 32; ++j) {
      asm("" : "+v"(w0[j]));
      asm("" : "+v"(w1[j]));
      asm("" : "+v"(w2[j]));
    }
    const float bh0 = bhh[g], bh1 = bhh[g + 256], bh2 = bhh[g + 512];
    if (t < 256) hbuf[0][t] = 0.f;
    float h_old = 0.f;
    const float* giB = gi + (size_t)(b * S_) * 768;
    float* hsB = hs + (size_t)b * 256;
    float ir = giB[g], iz = giB[g + 256], in_ = giB[g + 512];
    __syncthreads();

    for (int s = 0; s < S_; ++s) {
      const int cur = s & 1, nxt = cur ^ 1;
      const int sn = (s + 1 < S_) ? s + 1 : s;
      const float irn = giB[(size_t)sn * 768 + g];
      const float izn = giB[(size_t)sn * 768 + g + 256];
      const float inn = giB[(size_t)sn * 768 + g + 512];

      f32x2 a0 = {0.f, 0.f}, a1 = a0, a2 = a0;
#pragma unroll
      for (int j = 0; j < 16; ++j) {
        const int jr = (j + 2 * c) & 15;
        f32x4 hv = *(const f32x4*)&hbuf[cur][64 * c + 4 * jr];
        f32x2 hA = {hv[0], hv[1]}, hB = {hv[2], hv[3]};
        a0 = pkfma(w0[2 * j], hA, a0); a0 = pkfma(w0[2 * j + 1], hB, a0);
        a1 = pkfma(w1[2 * j], hA, a1); a1 = pkfma(w1[2 * j + 1], hB, a1);
        a2 = pkfma(w2[2 * j], hA, a2); a2 = pkfma(w2[2 * j + 1], hB, a2);
      }
      float d0 = (a0[0] + a0[1]);
      float d1 = (a1[0] + a1[1]);
      float d2 = (a2[0] + a2[1]);
      d0 += __shfl_xor(d0, 1); d0 += __shfl_xor(d0, 2);
      d1 += __shfl_xor(d1, 1); d1 += __shfl_xor(d1, 2);
      d2 += __shfl_xor(d2, 1); d2 += __shfl_xor(d2, 2);

      const float r = fsig(ir + d0 + bh0);
      const float z = fsig(iz + d1 + bh1);
      const float n = ftanh(in_ + r * (d2 + bh2));
      const float hn = (1.f - z) * n + z * h_old;
      h_old = hn;

      float* hsrow = hsB + (size_t)s * 512;
      if (c == 0) {
        hbuf[nxt][g] = hn;
        __hip_atomic_store(hsrow + g, hn, __ATOMIC_RELAXED, __HIP_MEMORY_SCOPE_AGENT);
      }
      if (t < 128) {
        const int pg = (half ^ 1) * 128 + t;
        float v;
        do {
          v = __hip_atomic_load(hsrow + pg, __ATOMIC_RELAXED, __HIP_MEMORY_SCOPE_AGENT);
        } while (v != v);
        hbuf[nxt][pg] = v;
      }
      ir = irn; iz = izn; in_ = inn;
      __syncthreads();
    }
    if (c == 0) newh[b * 256 + g] = h_old;

  } else if (bid < 16 + nGemm) {
    // -------- dense gate-up path (all experts, hidden under the scan) --------
    const int bi = bid - 16;
    const int e = bi >> 10, r = bi & 1023;      // 1024 = 32x32 tiles per expert
    const int m0 = (r & 31) * 128, n0 = (r >> 5) * 128;
    __bf16* sA = (__bf16*)smem;
    __bf16* sB = sA + 128 * 64;
    __bf16* sC = sB + 128 * 64;
    const int t = threadIdx.x;
    const float* wg = Wg + (size_t)e * HH_ * D_;
    const float* wu = Wu + (size_t)e * HH_ * D_;
    f32x4 ag[4][4] = {}, au[4][4] = {};
    for (int kt = 0; kt < D_ / 64; ++kt) {
      __syncthreads();
      if (t < 256) {
        stage128x64(sA, xbf + (size_t)m0 * D_ + kt * 64, D_, t);
        stage128x64_cvt(sB, wg + (size_t)n0 * D_ + kt * 64, D_, t);
        stage128x64_cvt(sC, wu + (size_t)n0 * D_ + kt * 64, D_, t);
      }
      __syncthreads();
      if (t < 256) mfma_tile2(sA, sB, sC, ag, au, t);
    }
    if (t < 256) {
      const int w = t >> 6, l = t & 63, wr = w >> 1, wc = w & 1;
      const int col = l & 15, rb = (l >> 4) * 4;
#pragma unroll
      for (int m = 0; m < 4; ++m)
#pragma unroll
        for (int n = 0; n < 4; ++n)
#pragma unroll
          for (int i = 0; i < 4; ++i) {
            int gm = m0 + 64 * wr + 16 * m + rb + i;    // token index
            int gn = n0 + 64 * wc + 16 * n + col;
            float gv = ag[m][n][i], uv = au[m][n][i];
            float h = 0.5f * gv * (1.f + erff(gv * 0.70710678118654752440f)) * uv;
            Hall[((size_t)e * 4096 + gm) * HH_ + gn] = (__bf16)h;
          }
    }

  } else {
    // -------- Wd f32->bf16 convert path --------
    const int bi2 = bid - 16 - nGemm;
    const size_t base = (size_t)bi2 * 512 + threadIdx.x;
#pragma unroll
    for (int k2 = 0; k2 < 4; ++k2) {
      const size_t u = base + (size_t)k2 * 2097152;  // f32x4 units, 8.39M total
      f32x4 v = ((const f32x4*)Wd)[u];
      bf16x4 o;
#pragma unroll
      for (int j = 0; j < 4; ++j) o[j] = (__bf16)v[j];
      ((bf16x4*)Wdbf)[u] = o;
    }
  }
}

// ---------------------------------------------------------------- router (logits+finish+build)
__global__ void k_router(const float* __restrict__ hs, const float* __restrict__ Wr,
                         const float* __restrict__ br, float* __restrict__ logits,
                         float* __restrict__ wdense, int* __restrict__ cnt,
                         int* __restrict__ list, float* __restrict__ partials) {
  const int tok = blockIdx.x * 256 + threadIdx.x;  // 4096
  const int s = tok & (S_ - 1), b = tok >> 11;
  const f32x4* h4 = (const f32x4*)&hs[((size_t)s * 2 + b) * 256];
  float p[8];
  float mx = -1e30f;
#pragma unroll
  for (int e = 0; e < 8; ++e) {
    const f32x4* w4 = (const f32x4*)&Wr[e * 256];
    float acc = 0.f;
#pragma unroll 8
    for (int k = 0; k < 64; ++k) {
      f32x4 a = h4[k], w = w4[k];
      acc += a[0] * w[0] + a[1] * w[1] + a[2] * w[2] + a[3] * w[3];
    }
    acc += br[e];
    logits[tok * 8 + e] = acc;
    p[e] = acc;
    mx = fmaxf(mx, acc);
  }
  float sum = 0.f;
#pragma unroll
  for (int e = 0; e < 8; ++e) { p[e] = expf(p[e] - mx); sum += p[e]; }
  const float inv = 1.f / sum;
#pragma unroll
  for (int e = 0; e < 8; ++e) p[e] *= inv;
  int i1 = 0;
#pragma unroll
  for (int e = 1; e < 8; ++e) if (p[e] > p[i1]) i1 = e;   // ties -> lower index
  int i2 = -1; float p2 = -1.f;
#pragma unroll
  for (int e = 0; e < 8; ++e) if (e != i1 && p[e] > p2) { p2 = p[e]; i2 = e; }
  const float inv2 = 1.f / (p[i1] + p2);
#pragma unroll
  for (int e = 0; e < 8; ++e)
    wdense[tok * 8 + e] = (e == i1) ? p[i1] * inv2 : (e == i2 ? p2 * inv2 : 0.f);
  {
    int pos = atomicAdd(&cnt[i1], 1);
    list[i1 * 4096 + pos] = tok;
    pos = atomicAdd(&cnt[i2], 1);
    list[i2 * 4096 + pos] = tok;
  }

  __shared__ float ps[256][8];
#pragma unroll
  for (int e = 0; e < 8; ++e) ps[threadIdx.x][e] = p[e];
  __syncthreads();
  for (int st = 128; st >= 1; st >>= 1) {
    if (threadIdx.x < st)
#pragma unroll
      for (int e = 0; e < 8; ++e) ps[threadIdx.x][e] += ps[threadIdx.x + st][e];
    __syncthreads();
  }
  if (threadIdx.x == 0)
#pragma unroll
    for (int e = 0; e < 8; ++e) partials[blockIdx.x * 8 + e] = ps[0][e];
}

__global__ void k_aux(const float* __restrict__ partials, float* __restrict__ aux) {
  __shared__ float m2[8];
  const int e = threadIdx.x;
  if (e < 8) {
    float s = 0.f;
    for (int bl = 0; bl < 16; ++bl) s += partials[bl * 8 + e];
    const float mean = s / 4096.f;
    m2[e] = mean * mean;
  }
  __syncthreads();
  if (threadIdx.x == 0) {
    float s = 0.f;
#pragma unroll
    for (int i = 0; i < 8; ++i) s += m2[i];
    aux[0] = 8.f * s;
  }
}

// ---------------------------------------------------------------- fallback dense gate-up
__global__ __launch_bounds__(256, 2)
void k_gateup_d(const __bf16* __restrict__ xbf, const float* __restrict__ Wg,
                const float* __restrict__ Wu, __bf16* __restrict__ Hout) {
  __shared__ __bf16 sA[128 * 64], sB[128 * 64], sC[128 * 64];
  const int t = threadIdx.x;
  const int m0 = blockIdx.x * 128, n0 = blockIdx.y * 128;
  f32x4 ag[4][4] = {}, au[4][4] = {};
  for (int kt = 0; kt < D_ / 64; ++kt) {
    __syncthreads();
    stage128x64(sA, xbf + (size_t)m0 * D_ + kt * 64, D_, t);
    stage128x64_cvt(sB, Wg + (size_t)n0 * D_ + kt * 64, D_, t);
    stage128x64_cvt(sC, Wu + (size_t)n0 * D_ + kt * 64, D_, t);
    __syncthreads();
    mfma_tile2(sA, sB, sC, ag, au, t);
  }
  const int w = t >> 6, l = t & 63, wr = w >> 1, wc = w & 1;
  const int col = l & 15, rb = (l >> 4) * 4;
#pragma unroll
  for (int m = 0; m < 4; ++m)
#pragma unroll
    for (int n = 0; n < 4; ++n)
#pragma unroll
      for (int i = 0; i < 4; ++i) {
        int gm = m0 + 64 * wr + 16 * m + rb + i;
        int gn = n0 + 64 * wc + 16 * n + col;
        float gv = ag[m][n][i], uv = au[m][n][i];
        float h = 0.5f * gv * (1.f + erff(gv * 0.70710678118654752440f)) * uv;
        Hout[(size_t)gm * HH_ + gn] = (__bf16)h;
      }
}

// ---------------------------------------------------------------- sparse down
// z-batched over experts; atomic out accumulation (two experts per token run
// concurrently). out starts 0, exactly 2 commutative float adds per element.
__global__ __launch_bounds__(256, 2)
void k_down_s(const __bf16* __restrict__ Hbase, const __bf16* __restrict__ Wdbase,
              const float* __restrict__ wdense, const int* __restrict__ list,
              const int* __restrict__ cnt, float* __restrict__ out,
              int eBase, int hRowsPerE, long long wStridePerE) {
  __shared__ __bf16 sA[128 * 64], sB[128 * 64];
  __shared__ int rowtok[128];
  const int e = eBase + blockIdx.z;
  const int t = threadIdx.x;
  const int m0 = blockIdx.x * 128, n0 = blockIdx.y * 128;
  const int ce = cnt[e];
  if (m0 >= ce) return;
  if (t < 128) rowtok[t] = list[e * 4096 + m0 + t];
  const __bf16* Hrows = Hbase + (size_t)e * hRowsPerE * HH_;
  const __bf16* Wde = Wdbase + (size_t)e * (size_t)wStridePerE;
  f32x4 acc[4][4] = {};
  for (int kt = 0; kt < HH_ / 64; ++kt) {
    __syncthreads();
    stage128x64_gather(sA, Hrows, HH_, kt * 64, rowtok, t);
    stage128x64(sB, Wde + (size_t)n0 * HH_ + kt * 64, HH_, t);
    __syncthreads();
    mfma_tile(sA, sB, acc, t);
  }
  const int w = t >> 6, l = t & 63, wr = w >> 1, wc = w & 1;
  const int col = l & 15, rb = (l >> 4) * 4;
#pragma unroll
  for (int m = 0; m < 4; ++m)
#pragma unroll
    for (int i = 0; i < 4; ++i) {
      const int lr = 64 * wr + 16 * m + rb + i;
      if (m0 + lr < ce) {
        const int tok = rowtok[lr];
        const float wv = wdense[tok * 8 + e];
#pragma unroll
        for (int n = 0; n < 4; ++n) {
          const int gn = n0 + 64 * wc + 16 * n + col;
          atomicAdd(&out[(size_t)tok * 1024 + gn], wv * acc[m][n][i]);
        }
      }
    }
}

// ---------------------------------------------------------------- launch
extern "C" void kernel_launch(void* const* d_in, const int* in_sizes, int n_in,
                              void* d_out, int out_size, void* d_ws, size_t ws_size,
                              hipStream_t stream) {
  (void)in_sizes; (void)n_in; (void)out_size;
  const float* x    = (const float*)d_in[0];
  const float* Wg   = (const float*)d_in[1];
  const float* Wu   = (const float*)d_in[2];
  const float* Wd   = (const float*)d_in[3];
  const float* Wih  = (const float*)d_in[4];
  const float* Whh  = (const float*)d_in[5];
  const float* bih  = (const float*)d_in[6];
  const float* bhh  = (const float*)d_in[7];
  const float* Wr   = (const float*)d_in[8];
  const float* br   = (const float*)d_in[9];

  float* out    = (float*)d_out;                       // (B,S,D)
  float* logits = out + (size_t)B_ * S_ * D_;          // (B,S,E)
  float* newh   = logits + (size_t)B_ * S_ * E_;       // (B,RH)
  float* aux    = newh + (size_t)B_ * RH_;             // scalar

  char* ws = (char*)d_ws;
  size_t off = 0;
  auto alloc = [&](size_t bytes) { size_t r = off; off += (bytes + 255) & ~(size_t)255; return r; };
  const size_t XN = (size_t)B_ * S_ * D_;              // 4,194,304
  const size_t WIN = (size_t)3 * RH_ * D_;             // 786,432

  // ---- common buffers ----
  __bf16* xh  = (__bf16*)(ws + alloc(XN * 2));
  __bf16* xm  = (__bf16*)(ws + alloc(XN * 2));
  __bf16* xl  = (__bf16*)(ws + alloc(XN * 2));
  __bf16* wih_h = (__bf16*)(ws + alloc(WIN * 2));
  __bf16* wih_m = (__bf16*)(ws + alloc(WIN * 2));
  __bf16* wih_l = (__bf16*)(ws + alloc(WIN * 2));
  float*  gi  = (float*)(ws + alloc((size_t)B_ * S_ * 768 * 4));
  float*  hs  = (float*)(ws + alloc((size_t)S_ * B_ * RH_ * 4));
  float*  wdense = (float*)(ws + alloc((size_t)B_ * S_ * E_ * 4));
  int*    cnt  = (int*)(ws + alloc(E_ * 4));
  int*    list = (int*)(ws + alloc((size_t)E_ * 4096 * 4));
  float*  partials = (float*)(ws + alloc(16 * 8 * 4));
  const size_t commonEnd = off;

  // fused-path sizes
  const size_t szWdbfAll = (size_t)E_ * D_ * HH_ * 2;      // 67 MB
  const size_t szHall    = (size_t)E_ * 4096 * HH_ * 2;    // 268 MB
  const bool fused = (commonEnd + szWdbfAll + szHall + 512) <= ws_size;

  hipMemsetAsync(out, 0, XN * 4, stream);
  hipMemsetAsync(hs, 0xFF, (size_t)S_ * B_ * RH_ * 4, stream);  // NaN-poison
  hipMemsetAsync(cnt, 0, E_ * 4, stream);
  hipMemsetAsync(list, 0, (size_t)E_ * 4096 * 4, stream);

  k_split3<<<dim3((XN / 4 + 255) / 256), 256, 0, stream>>>(x, xh, xm, xl, (int)(XN / 4));
  k_split3<<<dim3((WIN / 4 + 255) / 256), 256, 0, stream>>>(Wih, wih_h, wih_m, wih_l, (int)(WIN / 4));
  k_gemm_gi<<<dim3(32, 6), 256, 0, stream>>>(xh, xm, xl, wih_h, wih_m, wih_l, bih, gi);

  if (fused) {
    __bf16* WdbfA = (__bf16*)(ws + alloc(szWdbfAll));
    __bf16* Hall  = (__bf16*)(ws + alloc(szHall));
    const int nGemm = E_ * 32 * 32;      // 8192
    const int nCvt  = 4096;
    // scan || dense gate-up (all experts) || Wd convert — one launch
    k_fused<<<dim3(16 + nGemm + nCvt), 512, 0, stream>>>(
        Whh, gi, bhh, hs, newh, xh, Wg, Wu, Hall, Wd, WdbfA, nGemm);
    k_router<<<dim3(16), 256, 0, stream>>>(hs, Wr, br, logits, wdense, cnt, list, partials);
    k_aux<<<dim3(1), 64, 0, stream>>>(partials, aux);
    // sparse down for all experts in one z-batched launch (atomic scatter-add)
    k_down_s<<<dim3(32, 8, 8), 256, 0, stream>>>(
        Hall, WdbfA, wdense, list, cnt, out, 0, 4096, (long long)D_ * HH_);
  } else {
    __bf16* Wdbf = (__bf16*)(ws + alloc((size_t)D_ * HH_ * 2));
    __bf16* Htmp = (__bf16*)(ws + alloc((size_t)B_ * S_ * HH_ * 2));
    // scan only (fused kernel with grid=16 runs just the scan roles)
    k_fused<<<dim3(16), 512, 0, stream>>>(
        Whh, gi, bhh, hs, newh, xh, Wg, Wu, Htmp, Wd, Wdbf, 0);
    k_router<<<dim3(16), 256, 0, stream>>>(hs, Wr, br, logits, wdense, cnt, list, partials);
    k_aux<<<dim3(1), 64, 0, stream>>>(partials, aux);
    const int n4w = (int)((size_t)HH_ * D_ / 4);
    for (int e = 0; e < E_; ++e) {
      const size_t wo = (size_t)e * HH_ * D_;
      k_cvt1<<<dim3((n4w + 255) / 256), 256, 0, stream>>>(Wd + wo, Wdbf, n4w);
      k_gateup_d<<<dim3(32, 32), 256, 0, stream>>>(xh, Wg + wo, Wu + wo, Htmp);
      k_down_s<<<dim3(32, 8, 1), 256, 0, stream>>>(
          Htmp, Wdbf, wdense, list, cnt, out, e, 0, 0);
    }
  }
}